// Round 2
// baseline (779.527 us; speedup 1.0000x reference)
//
#include <hip/hip_runtime.h>

#define NN 50000
#define NE 800000
#define D  64

// deg[dst] += w  (self-loop +1 folded into dinv_kernel)
__global__ void deg_kernel(const int* __restrict__ dst, const float* __restrict__ w,
                           float* __restrict__ deg) {
    int e = blockIdx.x * blockDim.x + threadIdx.x;
    if (e < NE) {
        unsigned d = (unsigned)dst[e];
        if (d < NN) atomicAdd(&deg[d], w[e]);
    }
}

// deg -> rsqrt(deg + 1)   (in place; +1 is the self-loop weight)
__global__ void dinv_kernel(float* __restrict__ deg) {
    int i = blockIdx.x * blockDim.x + threadIdx.x;
    if (i < NN) deg[i] = rsqrtf(deg[i] + 1.0f);
}

// h[N,64] = x[N,64] @ W[64,64].  256 thr = 4 rows x 64 cols, W staged in LDS.
__global__ void gemm_kernel(const float* __restrict__ x, const float* __restrict__ W,
                            float* __restrict__ h) {
    __shared__ float Ws[D * D];
    __shared__ float xs[4][D];
    int t = threadIdx.x;
    for (int i = t; i < D * D; i += 256) Ws[i] = W[i];
    int row = t >> 6, col = t & 63;
    int r = blockIdx.x * 4 + row;
    xs[row][col] = x[(size_t)r * D + col];
    __syncthreads();
    float sum = 0.f;
#pragma unroll
    for (int k = 0; k < D; ++k) sum += xs[row][k] * Ws[k * D + col];
    h[(size_t)r * D + col] = sum;
}

// y[n,f] = h[n,f] * dinv[n]^2   (self-loop contribution, also zero-inits y)
__global__ void selfloop_kernel(const float* __restrict__ h, const float* __restrict__ dinv,
                                float* __restrict__ y) {
    int idx = blockIdx.x * blockDim.x + threadIdx.x;
    if (idx < NN * D) {
        int n = idx >> 6;
        float di = dinv[n];
        y[idx] = h[idx] * di * di;
    }
}

// one wave per edge, lane = feature: y[dst,f] += h[src,f] * dinv[s]*w*dinv[d]
__global__ void scatter_kernel(const int* __restrict__ src, const int* __restrict__ dst,
                               const float* __restrict__ w, const float* __restrict__ dinv,
                               const float* __restrict__ h, float* __restrict__ y) {
    int t = blockIdx.x * blockDim.x + threadIdx.x;
    int e = t >> 6;
    int f = t & 63;
    if (e < NE) {
        unsigned s = (unsigned)src[e];
        unsigned d = (unsigned)dst[e];
        if (s < NN && d < NN) {
            float coef = dinv[s] * w[e] * dinv[d];
            atomicAdd(&y[(size_t)d * D + f], h[(size_t)s * D + f] * coef);
        }
    }
}

// x = relu(y + b)  in place
__global__ void biasrelu_kernel(float* __restrict__ y, const float* __restrict__ b) {
    int idx = blockIdx.x * blockDim.x + threadIdx.x;
    if (idx < NN * D) {
        float v = y[idx] + b[idx & 63];
        y[idx] = v > 0.f ? v : 0.f;
    }
}

extern "C" void kernel_launch(void* const* d_in, const int* in_sizes, int n_in,
                              void* d_out, int out_size, void* d_ws, size_t ws_size,
                              hipStream_t stream) {
    const float* x   = (const float*)d_in[0];
    const int*   ei  = (const int*)d_in[1];    // int inputs delivered as int32; [2, NE] flat
    const float* ew  = (const float*)d_in[2];
    const float* W0  = (const float*)d_in[3];
    const float* b0  = (const float*)d_in[4];
    const float* W1  = (const float*)d_in[5];
    const float* b1  = (const float*)d_in[6];
    const float* W2  = (const float*)d_in[7];
    const float* b2  = (const float*)d_in[8];
    float*       out = (float*)d_out;

    // workspace layout (floats): dinv[NN] | h[NN*D] | xb[NN*D]  (~26 MB worst case,
    // but xb only needed for layer 0 accumulator -> total used ~26 MB if available;
    // layout keeps within dinv+h+xb)
    float* ws   = (float*)d_ws;
    float* dinv = ws;
    float* h    = ws + NN;
    float* xb   = h + (size_t)NN * D;

    const int* src = ei;
    const int* dst = ei + NE;

    // normalization coefficients
    hipMemsetAsync(dinv, 0, NN * sizeof(float), stream);
    deg_kernel<<<(NE + 255) / 256, 256, 0, stream>>>(dst, ew, dinv);
    dinv_kernel<<<(NN + 255) / 256, 256, 0, stream>>>(dinv);

    // layer 0: in=x -> acc=xb
    gemm_kernel<<<NN / 4, 256, 0, stream>>>(x, W0, h);
    selfloop_kernel<<<(NN * D) / 256, 256, 0, stream>>>(h, dinv, xb);
    scatter_kernel<<<((size_t)NE * 64) / 256, 256, 0, stream>>>(src, dst, ew, dinv, h, xb);
    biasrelu_kernel<<<(NN * D) / 256, 256, 0, stream>>>(xb, b0);

    // layer 1: in=xb -> acc=out
    gemm_kernel<<<NN / 4, 256, 0, stream>>>(xb, W1, h);
    selfloop_kernel<<<(NN * D) / 256, 256, 0, stream>>>(h, dinv, out);
    scatter_kernel<<<((size_t)NE * 64) / 256, 256, 0, stream>>>(src, dst, ew, dinv, h, out);
    biasrelu_kernel<<<(NN * D) / 256, 256, 0, stream>>>(out, b1);

    // layer 2: in=out -> acc=out (gemm reads out fully before selfloop overwrites; stream-ordered)
    gemm_kernel<<<NN / 4, 256, 0, stream>>>(out, W2, h);
    selfloop_kernel<<<(NN * D) / 256, 256, 0, stream>>>(h, dinv, out);
    scatter_kernel<<<((size_t)NE * 64) / 256, 256, 0, stream>>>(src, dst, ew, dinv, h, out);
    biasrelu_kernel<<<(NN * D) / 256, 256, 0, stream>>>(out, b2);
}

// Round 3
// 499.661 us; speedup vs baseline: 1.5601x; 1.5601x over previous
//
#include <hip/hip_runtime.h>

#define NN 50000
#define NE 800000
#define D  64
#define SCAN_B 98   // ceil(NN / 512)

// counts[dst]++ ; deg[dst] += w
__global__ void hist_kernel(const int* __restrict__ dst, const float* __restrict__ w,
                            int* __restrict__ counts, float* __restrict__ deg) {
    int e = blockIdx.x * blockDim.x + threadIdx.x;
    if (e < NE) {
        unsigned d = (unsigned)dst[e];
        if (d < NN) {
            atomicAdd(&counts[d], 1);
            atomicAdd(&deg[d], w[e]);
        }
    }
}

// deg -> rsqrt(deg + 1)   (+1 = self-loop weight)
__global__ void dinv_kernel(float* __restrict__ deg) {
    int i = blockIdx.x * blockDim.x + threadIdx.x;
    if (i < NN) deg[i] = rsqrtf(deg[i] + 1.0f);
}

// per-block (512 counts) totals
__global__ void scan_partial_kernel(const int* __restrict__ counts, int* __restrict__ blocksum) {
    __shared__ int sd[256];
    int t = threadIdx.x;
    int base = blockIdx.x * 512;
    int i0 = base + t, i1 = base + t + 256;
    int v = 0;
    if (i0 < NN) v += counts[i0];
    if (i1 < NN) v += counts[i1];
    sd[t] = v;
    __syncthreads();
    for (int off = 128; off > 0; off >>= 1) {
        if (t < off) sd[t] += sd[t + off];
        __syncthreads();
    }
    if (t == 0) blocksum[blockIdx.x] = sd[0];
}

// exclusive scan of the 98 block totals (one block, 128 threads)
__global__ void scan_block_kernel(const int* __restrict__ blocksum, int* __restrict__ blockoff) {
    __shared__ int sd[128];
    int t = threadIdx.x;
    int v = (t < SCAN_B) ? blocksum[t] : 0;
    sd[t] = v;
    __syncthreads();
    for (int off = 1; off < 128; off <<= 1) {
        int add = (t >= off) ? sd[t - off] : 0;
        __syncthreads();
        sd[t] += add;
        __syncthreads();
    }
    if (t < SCAN_B) blockoff[t] = sd[t] - v;   // exclusive
}

// local exclusive scan (512 counts, pairs per thread) + block offset -> row_start & cursor
__global__ void scan_emit_kernel(const int* __restrict__ counts, const int* __restrict__ blockoff,
                                 int* __restrict__ row_start, int* __restrict__ cursor) {
    __shared__ int sd[256];
    int t = threadIdx.x;
    int base = blockIdx.x * 512;
    int i0 = base + 2 * t, i1 = i0 + 1;
    int c0 = (i0 < NN) ? counts[i0] : 0;
    int c1 = (i1 < NN) ? counts[i1] : 0;
    int s = c0 + c1;
    sd[t] = s;
    __syncthreads();
    for (int off = 1; off < 256; off <<= 1) {
        int add = (t >= off) ? sd[t - off] : 0;
        __syncthreads();
        sd[t] += add;
        __syncthreads();
    }
    int excl = sd[t] - s + blockoff[blockIdx.x];
    if (i0 < NN) { row_start[i0] = excl;      cursor[i0] = excl; }
    if (i1 < NN) { row_start[i1] = excl + c0; cursor[i1] = excl + c0; }
    if (blockIdx.x == 0 && t == 0) row_start[NN] = NE;
}

// scatter edges into CSR slots (order within a row irrelevant)
__global__ void fill_kernel(const int* __restrict__ src, const int* __restrict__ dst,
                            const float* __restrict__ w, int* __restrict__ cursor,
                            int* __restrict__ csr_src, float* __restrict__ csr_w) {
    int e = blockIdx.x * blockDim.x + threadIdx.x;
    if (e < NE) {
        unsigned d = (unsigned)dst[e];
        unsigned s = (unsigned)src[e];
        if (d < NN && s < NN) {
            int pos = atomicAdd(&cursor[d], 1);
            csr_src[pos] = (int)s;
            csr_w[pos]   = w[e];
        }
    }
}

// hp[N,64] = dinv[r] * (x[N,64] @ W[64,64]); 16 rows/block, W column in VGPRs
__global__ __launch_bounds__(256) void gemm_pre_kernel(const float* __restrict__ x,
        const float* __restrict__ W, const float* __restrict__ dinv, float* __restrict__ hp) {
    __shared__ float xs[16][64];
    int t = threadIdx.x;
    int base = blockIdx.x * 16;
    for (int idx = t; idx < 16 * 64; idx += 256)
        xs[idx >> 6][idx & 63] = x[(size_t)(base + (idx >> 6)) * 64 + (idx & 63)];
    __syncthreads();
    int col = t & 63, rq = t >> 6;
    float wc[64];
#pragma unroll
    for (int k = 0; k < 64; ++k) wc[k] = W[k * 64 + col];   // coalesced, L1-resident
    float acc0 = 0.f, acc1 = 0.f, acc2 = 0.f, acc3 = 0.f;
#pragma unroll
    for (int k = 0; k < 64; ++k) {
        float wk = wc[k];
        acc0 += xs[rq     ][k] * wk;   // LDS broadcast (wave-uniform addr) -> conflict-free
        acc1 += xs[rq +  4][k] * wk;
        acc2 += xs[rq +  8][k] * wk;
        acc3 += xs[rq + 12][k] * wk;
    }
    int r = base + rq;
    hp[(size_t)(r     ) * 64 + col] = dinv[r     ] * acc0;
    hp[(size_t)(r +  4) * 64 + col] = dinv[r +  4] * acc1;
    hp[(size_t)(r +  8) * 64 + col] = dinv[r +  8] * acc2;
    hp[(size_t)(r + 12) * 64 + col] = dinv[r + 12] * acc3;
}

// one wave per node: out[n] = relu(dinv[n]*(sum_e w_e*hp[src_e] + hp[n]) + b)
__global__ __launch_bounds__(256) void gather_kernel(const int* __restrict__ row_start,
        const int* __restrict__ csr_src, const float* __restrict__ csr_w,
        const float* __restrict__ dinv, const float* __restrict__ hp,
        const float* __restrict__ b, float* __restrict__ out) {
    int t = threadIdx.x;
    int n = blockIdx.x * 4 + (t >> 6);
    int lane = t & 63;
    int s0 = row_start[n], s1 = row_start[n + 1];
    float acc = hp[(size_t)n * 64 + lane];     // self-loop term (pre-scaled)
    for (int j = s0; j < s1; ++j) {
        int s = csr_src[j];
        float wv = csr_w[j];
        acc += wv * hp[(size_t)s * 64 + lane]; // coalesced 256B gather per edge
    }
    float v = dinv[n] * acc + b[lane];
    out[(size_t)n * 64 + lane] = v > 0.f ? v : 0.f;
}

extern "C" void kernel_launch(void* const* d_in, const int* in_sizes, int n_in,
                              void* d_out, int out_size, void* d_ws, size_t ws_size,
                              hipStream_t stream) {
    const float* x  = (const float*)d_in[0];
    const int*   ei = (const int*)d_in[1];    // int32 [2, NE] flat
    const float* ew = (const float*)d_in[2];
    const float* W0 = (const float*)d_in[3];
    const float* b0 = (const float*)d_in[4];
    const float* W1 = (const float*)d_in[5];
    const float* b1 = (const float*)d_in[6];
    const float* W2 = (const float*)d_in[7];
    const float* b2 = (const float*)d_in[8];
    float*       out = (float*)d_out;

    const int* src = ei;
    const int* dst = ei + NE;

    // workspace layout (all 4-byte elems), ~20.0 MB total
    float* dinv      = (float*)d_ws;                 // NN   (doubles as deg accumulator)
    int*   counts    = (int*)(dinv + NN);            // NN   (adjacent to dinv for single memset)
    int*   row_start = counts + NN;                  // NN+1
    int*   cursor    = row_start + NN + 1;           // NN
    int*   blocksum  = cursor + NN;                  // 128
    int*   blockoff  = blocksum + 128;               // 128
    int*   csr_src   = blockoff + 128;               // NE
    float* csr_w     = (float*)(csr_src + NE);       // NE
    float* hp        = csr_w + NE;                   // NN*64

    // ---- CSR build (once; shared by all 3 layers) ----
    hipMemsetAsync(dinv, 0, 2 * NN * sizeof(float), stream);   // dinv + counts
    hist_kernel<<<(NE + 255) / 256, 256, 0, stream>>>(dst, ew, counts, dinv);
    dinv_kernel<<<(NN + 255) / 256, 256, 0, stream>>>(dinv);
    scan_partial_kernel<<<SCAN_B, 256, 0, stream>>>(counts, blocksum);
    scan_block_kernel<<<1, 128, 0, stream>>>(blocksum, blockoff);
    scan_emit_kernel<<<SCAN_B, 256, 0, stream>>>(counts, blockoff, row_start, cursor);
    fill_kernel<<<(NE + 255) / 256, 256, 0, stream>>>(src, dst, ew, cursor, csr_src, csr_w);

    // ---- layer 0: x -> out ----
    gemm_pre_kernel<<<NN / 16, 256, 0, stream>>>(x, W0, dinv, hp);
    gather_kernel<<<NN / 4, 256, 0, stream>>>(row_start, csr_src, csr_w, dinv, hp, b0, out);

    // ---- layer 1: out -> out (gemm consumes out before gather overwrites; stream-ordered) ----
    gemm_pre_kernel<<<NN / 16, 256, 0, stream>>>(out, W1, dinv, hp);
    gather_kernel<<<NN / 4, 256, 0, stream>>>(row_start, csr_src, csr_w, dinv, hp, b1, out);

    // ---- layer 2: out -> out ----
    gemm_pre_kernel<<<NN / 16, 256, 0, stream>>>(out, W2, dinv, hp);
    gather_kernel<<<NN / 4, 256, 0, stream>>>(row_start, csr_src, csr_w, dinv, hp, b2, out);
}

// Round 4
// 380.230 us; speedup vs baseline: 2.0501x; 1.3141x over previous
//
#include <hip/hip_runtime.h>

#define NN 50000
#define NE 800000
#define D  64
#define SCAN_B 98   // ceil(NN / 512)

// counts[dst]++ ; deg[dst] += w
__global__ void hist_kernel(const int* __restrict__ dst, const float* __restrict__ w,
                            int* __restrict__ counts, float* __restrict__ deg) {
    int e = blockIdx.x * blockDim.x + threadIdx.x;
    if (e < NE) {
        unsigned d = (unsigned)dst[e];
        if (d < NN) {
            atomicAdd(&counts[d], 1);
            atomicAdd(&deg[d], w[e]);
        }
    }
}

// deg -> rsqrt(deg + 1)   (+1 = self-loop weight)
__global__ void dinv_kernel(float* __restrict__ deg) {
    int i = blockIdx.x * blockDim.x + threadIdx.x;
    if (i < NN) deg[i] = rsqrtf(deg[i] + 1.0f);
}

// per-block (512 counts) totals
__global__ void scan_partial_kernel(const int* __restrict__ counts, int* __restrict__ blocksum) {
    __shared__ int sd[256];
    int t = threadIdx.x;
    int base = blockIdx.x * 512;
    int i0 = base + t, i1 = base + t + 256;
    int v = 0;
    if (i0 < NN) v += counts[i0];
    if (i1 < NN) v += counts[i1];
    sd[t] = v;
    __syncthreads();
    for (int off = 128; off > 0; off >>= 1) {
        if (t < off) sd[t] += sd[t + off];
        __syncthreads();
    }
    if (t == 0) blocksum[blockIdx.x] = sd[0];
}

// exclusive scan of the 98 block totals (one block, 128 threads)
__global__ void scan_block_kernel(const int* __restrict__ blocksum, int* __restrict__ blockoff) {
    __shared__ int sd[128];
    int t = threadIdx.x;
    int v = (t < SCAN_B) ? blocksum[t] : 0;
    sd[t] = v;
    __syncthreads();
    for (int off = 1; off < 128; off <<= 1) {
        int add = (t >= off) ? sd[t - off] : 0;
        __syncthreads();
        sd[t] += add;
        __syncthreads();
    }
    if (t < SCAN_B) blockoff[t] = sd[t] - v;   // exclusive
}

// local exclusive scan (512 counts) + block offset -> row_start & cursor
__global__ void scan_emit_kernel(const int* __restrict__ counts, const int* __restrict__ blockoff,
                                 int* __restrict__ row_start, int* __restrict__ cursor) {
    __shared__ int sd[256];
    int t = threadIdx.x;
    int base = blockIdx.x * 512;
    int i0 = base + 2 * t, i1 = i0 + 1;
    int c0 = (i0 < NN) ? counts[i0] : 0;
    int c1 = (i1 < NN) ? counts[i1] : 0;
    int s = c0 + c1;
    sd[t] = s;
    __syncthreads();
    for (int off = 1; off < 256; off <<= 1) {
        int add = (t >= off) ? sd[t - off] : 0;
        __syncthreads();
        sd[t] += add;
        __syncthreads();
    }
    int excl = sd[t] - s + blockoff[blockIdx.x];
    if (i0 < NN) { row_start[i0] = excl;      cursor[i0] = excl; }
    if (i1 < NN) { row_start[i1] = excl + c0; cursor[i1] = excl + c0; }
    if (blockIdx.x == 0 && t == 0) row_start[NN] = NE;
}

// scatter edges into packed CSR slots (src, w-bits) — one 8B store per edge
__global__ void fill_kernel(const int* __restrict__ src, const int* __restrict__ dst,
                            const float* __restrict__ w, int* __restrict__ cursor,
                            int2* __restrict__ csr_pk) {
    int e = blockIdx.x * blockDim.x + threadIdx.x;
    if (e < NE) {
        unsigned d = (unsigned)dst[e];
        unsigned s = (unsigned)src[e];
        if (d < NN && s < NN) {
            int pos = atomicAdd(&cursor[d], 1);
            int2 pk;
            pk.x = (int)s;
            pk.y = __float_as_int(w[e]);
            csr_pk[pos] = pk;
        }
    }
}

// hp[N,64] = dinv[r] * (x[N,64] @ W[64,64]); 16 rows/block, W column in VGPRs
__global__ __launch_bounds__(256) void gemm_pre_kernel(const float* __restrict__ x,
        const float* __restrict__ W, const float* __restrict__ dinv, float* __restrict__ hp) {
    __shared__ float xs[16][64];
    int t = threadIdx.x;
    int base = blockIdx.x * 16;
    for (int idx = t; idx < 16 * 64; idx += 256)
        xs[idx >> 6][idx & 63] = x[(size_t)(base + (idx >> 6)) * 64 + (idx & 63)];
    __syncthreads();
    int col = t & 63, rq = t >> 6;
    float wc[64];
#pragma unroll
    for (int k = 0; k < 64; ++k) wc[k] = W[k * 64 + col];   // coalesced, L1-resident
    float acc0 = 0.f, acc1 = 0.f, acc2 = 0.f, acc3 = 0.f;
#pragma unroll
    for (int k = 0; k < 64; ++k) {
        float wk = wc[k];
        acc0 += xs[rq     ][k] * wk;
        acc1 += xs[rq +  4][k] * wk;
        acc2 += xs[rq +  8][k] * wk;
        acc3 += xs[rq + 12][k] * wk;
    }
    int r = base + rq;
    hp[(size_t)(r     ) * 64 + col] = dinv[r     ] * acc0;
    hp[(size_t)(r +  4) * 64 + col] = dinv[r +  4] * acc1;
    hp[(size_t)(r +  8) * 64 + col] = dinv[r +  8] * acc2;
    hp[(size_t)(r + 12) * 64 + col] = dinv[r + 12] * acc3;
}

// one wave per node: lane-batched edge metadata + 8x unrolled independent gathers
__global__ __launch_bounds__(256) void gather_kernel(const int* __restrict__ row_start,
        const int2* __restrict__ csr_pk, const float* __restrict__ dinv,
        const float* __restrict__ hp, const float* __restrict__ b, float* __restrict__ out) {
    int t = threadIdx.x;
    int n = blockIdx.x * 4 + (t >> 6);
    int lane = t & 63;
    int s0 = row_start[n], s1 = row_start[n + 1];
    float acc0 = hp[(size_t)n * 64 + lane];     // self-loop term (pre-scaled)
    float acc1 = 0.f, acc2 = 0.f, acc3 = 0.f;
    for (int base = s0; base < s1; base += 64) {
        // each lane fetches one (src, w) pair of this chunk — coalesced dwordx2
        int j = base + lane;
        int  si = 0;
        float wl = 0.f;
        if (j < s1) {
            int2 pk = csr_pk[j];
            si = pk.x;
            wl = __int_as_float(pk.y);
        }
        int m = s1 - base; if (m > 64) m = 64;
        int jj = 0;
        for (; jj + 8 <= m; jj += 8) {
            int a0 = __shfl(si, jj + 0); float w0 = __shfl(wl, jj + 0);
            int a1 = __shfl(si, jj + 1); float w1 = __shfl(wl, jj + 1);
            int a2 = __shfl(si, jj + 2); float w2 = __shfl(wl, jj + 2);
            int a3 = __shfl(si, jj + 3); float w3 = __shfl(wl, jj + 3);
            int a4 = __shfl(si, jj + 4); float w4 = __shfl(wl, jj + 4);
            int a5 = __shfl(si, jj + 5); float w5 = __shfl(wl, jj + 5);
            int a6 = __shfl(si, jj + 6); float w6 = __shfl(wl, jj + 6);
            int a7 = __shfl(si, jj + 7); float w7 = __shfl(wl, jj + 7);
            float v0 = hp[(size_t)a0 * 64 + lane];
            float v1 = hp[(size_t)a1 * 64 + lane];
            float v2 = hp[(size_t)a2 * 64 + lane];
            float v3 = hp[(size_t)a3 * 64 + lane];
            float v4 = hp[(size_t)a4 * 64 + lane];
            float v5 = hp[(size_t)a5 * 64 + lane];
            float v6 = hp[(size_t)a6 * 64 + lane];
            float v7 = hp[(size_t)a7 * 64 + lane];
            acc0 += w0 * v0; acc1 += w1 * v1; acc2 += w2 * v2; acc3 += w3 * v3;
            acc0 += w4 * v4; acc1 += w5 * v5; acc2 += w6 * v6; acc3 += w7 * v7;
        }
        for (; jj < m; ++jj) {
            int a0 = __shfl(si, jj); float w0 = __shfl(wl, jj);
            acc0 += w0 * hp[(size_t)a0 * 64 + lane];
        }
    }
    float v = dinv[n] * (acc0 + acc1 + acc2 + acc3) + b[lane];
    out[(size_t)n * 64 + lane] = v > 0.f ? v : 0.f;
}

extern "C" void kernel_launch(void* const* d_in, const int* in_sizes, int n_in,
                              void* d_out, int out_size, void* d_ws, size_t ws_size,
                              hipStream_t stream) {
    const float* x  = (const float*)d_in[0];
    const int*   ei = (const int*)d_in[1];    // int32 [2, NE] flat
    const float* ew = (const float*)d_in[2];
    const float* W0 = (const float*)d_in[3];
    const float* b0 = (const float*)d_in[4];
    const float* W1 = (const float*)d_in[5];
    const float* b1 = (const float*)d_in[6];
    const float* W2 = (const float*)d_in[7];
    const float* b2 = (const float*)d_in[8];
    float*       out = (float*)d_out;

    const int* src = ei;
    const int* dst = ei + NE;

    // workspace layout (all 4-byte elems), ~20 MB total
    float* dinv      = (float*)d_ws;                 // NN   (doubles as deg accumulator)
    int*   counts    = (int*)(dinv + NN);            // NN
    int*   row_start = counts + NN;                  // NN+1
    int*   cursor    = row_start + NN + 1;           // NN
    int*   blocksum  = cursor + NN;                  // 128
    int*   blockoff  = blocksum + 128;               // 128
    int2*  csr_pk    = (int2*)(blockoff + 128);      // NE pairs (8B each)
    float* hp        = (float*)(csr_pk + NE);        // NN*64

    // ---- CSR build (once; shared by all 3 layers) ----
    hipMemsetAsync(dinv, 0, 2 * NN * sizeof(float), stream);   // dinv + counts
    hist_kernel<<<(NE + 255) / 256, 256, 0, stream>>>(dst, ew, counts, dinv);
    dinv_kernel<<<(NN + 255) / 256, 256, 0, stream>>>(dinv);
    scan_partial_kernel<<<SCAN_B, 256, 0, stream>>>(counts, blocksum);
    scan_block_kernel<<<1, 128, 0, stream>>>(blocksum, blockoff);
    scan_emit_kernel<<<SCAN_B, 256, 0, stream>>>(counts, blockoff, row_start, cursor);
    fill_kernel<<<(NE + 255) / 256, 256, 0, stream>>>(src, dst, ew, cursor, csr_pk);

    // ---- layer 0: x -> out ----
    gemm_pre_kernel<<<NN / 16, 256, 0, stream>>>(x, W0, dinv, hp);
    gather_kernel<<<NN / 4, 256, 0, stream>>>(row_start, csr_pk, dinv, hp, b0, out);

    // ---- layer 1: out -> out ----
    gemm_pre_kernel<<<NN / 16, 256, 0, stream>>>(out, W1, dinv, hp);
    gather_kernel<<<NN / 4, 256, 0, stream>>>(row_start, csr_pk, dinv, hp, b1, out);

    // ---- layer 2: out -> out ----
    gemm_pre_kernel<<<NN / 16, 256, 0, stream>>>(out, W2, dinv, hp);
    gather_kernel<<<NN / 4, 256, 0, stream>>>(row_start, csr_pk, dinv, hp, b2, out);
}

// Round 5
// 313.864 us; speedup vs baseline: 2.4836x; 1.2114x over previous
//
#include <hip/hip_runtime.h>

#define NN 50000
#define NE 800000
#define D  64
#define SCAN_B 98   // ceil(NN / 512)

// bf16 helpers (raw ushort storage, fp32 math)
__device__ __forceinline__ float b2f(unsigned short u) {
    return __uint_as_float((unsigned)u << 16);
}
__device__ __forceinline__ unsigned short f2b(float f) {   // round-to-nearest-even
    unsigned u = __float_as_uint(f);
    return (unsigned short)((u + 0x7FFFu + ((u >> 16) & 1u)) >> 16);
}

// counts[dst]++  (deg computed later from CSR — halves atomic write-through)
__global__ void hist_kernel(const int* __restrict__ dst, int* __restrict__ counts) {
    int e = blockIdx.x * blockDim.x + threadIdx.x;
    if (e < NE) {
        unsigned d = (unsigned)dst[e];
        if (d < NN) atomicAdd(&counts[d], 1);
    }
}

// per-block (512 counts) totals
__global__ void scan_partial_kernel(const int* __restrict__ counts, int* __restrict__ blocksum) {
    __shared__ int sd[256];
    int t = threadIdx.x;
    int base = blockIdx.x * 512;
    int i0 = base + t, i1 = base + t + 256;
    int v = 0;
    if (i0 < NN) v += counts[i0];
    if (i1 < NN) v += counts[i1];
    sd[t] = v;
    __syncthreads();
    for (int off = 128; off > 0; off >>= 1) {
        if (t < off) sd[t] += sd[t + off];
        __syncthreads();
    }
    if (t == 0) blocksum[blockIdx.x] = sd[0];
}

// exclusive scan of the 98 block totals (one block, 128 threads)
__global__ void scan_block_kernel(const int* __restrict__ blocksum, int* __restrict__ blockoff) {
    __shared__ int sd[128];
    int t = threadIdx.x;
    int v = (t < SCAN_B) ? blocksum[t] : 0;
    sd[t] = v;
    __syncthreads();
    for (int off = 1; off < 128; off <<= 1) {
        int add = (t >= off) ? sd[t - off] : 0;
        __syncthreads();
        sd[t] += add;
        __syncthreads();
    }
    if (t < SCAN_B) blockoff[t] = sd[t] - v;   // exclusive
}

// local exclusive scan (512 counts) + block offset -> row_start & cursor
__global__ void scan_emit_kernel(const int* __restrict__ counts, const int* __restrict__ blockoff,
                                 int* __restrict__ row_start, int* __restrict__ cursor) {
    __shared__ int sd[256];
    int t = threadIdx.x;
    int base = blockIdx.x * 512;
    int i0 = base + 2 * t, i1 = i0 + 1;
    int c0 = (i0 < NN) ? counts[i0] : 0;
    int c1 = (i1 < NN) ? counts[i1] : 0;
    int s = c0 + c1;
    sd[t] = s;
    __syncthreads();
    for (int off = 1; off < 256; off <<= 1) {
        int add = (t >= off) ? sd[t - off] : 0;
        __syncthreads();
        sd[t] += add;
        __syncthreads();
    }
    int excl = sd[t] - s + blockoff[blockIdx.x];
    if (i0 < NN) { row_start[i0] = excl;      cursor[i0] = excl; }
    if (i1 < NN) { row_start[i1] = excl + c0; cursor[i1] = excl + c0; }
    if (blockIdx.x == 0 && t == 0) row_start[NN] = NE;
}

// scatter edges into packed CSR slots (src, w-bits) — one 8B store per edge
__global__ void fill_kernel(const int* __restrict__ src, const int* __restrict__ dst,
                            const float* __restrict__ w, int* __restrict__ cursor,
                            int2* __restrict__ csr_pk) {
    int e = blockIdx.x * blockDim.x + threadIdx.x;
    if (e < NE) {
        unsigned d = (unsigned)dst[e];
        unsigned s = (unsigned)src[e];
        if (d < NN && s < NN) {
            int pos = atomicAdd(&cursor[d], 1);
            int2 pk;
            pk.x = (int)s;
            pk.y = __float_as_int(w[e]);
            csr_pk[pos] = pk;
        }
    }
}

// dinv[n] = rsqrt(1 + sum_{row n} w)  — contiguous reads, no atomics
__global__ void wdeg_kernel(const int* __restrict__ row_start, const int2* __restrict__ csr_pk,
                            float* __restrict__ dinv) {
    int n = blockIdx.x * blockDim.x + threadIdx.x;
    if (n < NN) {
        int s0 = row_start[n], s1 = row_start[n + 1];
        float s = 0.f;
        for (int j = s0; j < s1; ++j) s += __int_as_float(csr_pk[j].y);
        dinv[n] = rsqrtf(s + 1.0f);
    }
}

// hp[N,64] = bf16( dinv[r] * (x[N,64] @ W[64,64]) ); 16 rows/block, W column in VGPRs
__global__ __launch_bounds__(256) void gemm_pre_kernel(const float* __restrict__ x,
        const float* __restrict__ W, const float* __restrict__ dinv,
        unsigned short* __restrict__ hp) {
    __shared__ float xs[16][64];
    int t = threadIdx.x;
    int base = blockIdx.x * 16;
    for (int idx = t; idx < 16 * 64; idx += 256)
        xs[idx >> 6][idx & 63] = x[(size_t)(base + (idx >> 6)) * 64 + (idx & 63)];
    __syncthreads();
    int col = t & 63, rq = t >> 6;
    float wc[64];
#pragma unroll
    for (int k = 0; k < 64; ++k) wc[k] = W[k * 64 + col];   // coalesced, L1-resident
    float acc0 = 0.f, acc1 = 0.f, acc2 = 0.f, acc3 = 0.f;
#pragma unroll
    for (int k = 0; k < 64; ++k) {
        float wk = wc[k];
        acc0 += xs[rq     ][k] * wk;
        acc1 += xs[rq +  4][k] * wk;
        acc2 += xs[rq +  8][k] * wk;
        acc3 += xs[rq + 12][k] * wk;
    }
    int r = base + rq;
    hp[(size_t)(r     ) * 64 + col] = f2b(dinv[r     ] * acc0);
    hp[(size_t)(r +  4) * 64 + col] = f2b(dinv[r +  4] * acc1);
    hp[(size_t)(r +  8) * 64 + col] = f2b(dinv[r +  8] * acc2);
    hp[(size_t)(r + 12) * 64 + col] = f2b(dinv[r + 12] * acc3);
}

// one wave per node: lane-batched edge metadata + 8x unrolled bf16 row gathers
__global__ __launch_bounds__(256) void gather_kernel(const int* __restrict__ row_start,
        const int2* __restrict__ csr_pk, const float* __restrict__ dinv,
        const unsigned short* __restrict__ hp, const float* __restrict__ b,
        float* __restrict__ out) {
    int t = threadIdx.x;
    int n = blockIdx.x * 4 + (t >> 6);
    int lane = t & 63;
    int s0 = row_start[n], s1 = row_start[n + 1];
    float acc0 = b2f(hp[(size_t)n * 64 + lane]);   // self-loop term (pre-scaled)
    float acc1 = 0.f, acc2 = 0.f, acc3 = 0.f;
    for (int base = s0; base < s1; base += 64) {
        int j = base + lane;
        int  si = 0;
        float wl = 0.f;
        if (j < s1) {
            int2 pk = csr_pk[j];
            si = pk.x;
            wl = __int_as_float(pk.y);
        }
        int m = s1 - base; if (m > 64) m = 64;
        int jj = 0;
        for (; jj + 8 <= m; jj += 8) {
            int a0 = __shfl(si, jj + 0); float w0 = __shfl(wl, jj + 0);
            int a1 = __shfl(si, jj + 1); float w1 = __shfl(wl, jj + 1);
            int a2 = __shfl(si, jj + 2); float w2 = __shfl(wl, jj + 2);
            int a3 = __shfl(si, jj + 3); float w3 = __shfl(wl, jj + 3);
            int a4 = __shfl(si, jj + 4); float w4 = __shfl(wl, jj + 4);
            int a5 = __shfl(si, jj + 5); float w5 = __shfl(wl, jj + 5);
            int a6 = __shfl(si, jj + 6); float w6 = __shfl(wl, jj + 6);
            int a7 = __shfl(si, jj + 7); float w7 = __shfl(wl, jj + 7);
            float v0 = b2f(hp[(size_t)a0 * 64 + lane]);
            float v1 = b2f(hp[(size_t)a1 * 64 + lane]);
            float v2 = b2f(hp[(size_t)a2 * 64 + lane]);
            float v3 = b2f(hp[(size_t)a3 * 64 + lane]);
            float v4 = b2f(hp[(size_t)a4 * 64 + lane]);
            float v5 = b2f(hp[(size_t)a5 * 64 + lane]);
            float v6 = b2f(hp[(size_t)a6 * 64 + lane]);
            float v7 = b2f(hp[(size_t)a7 * 64 + lane]);
            acc0 += w0 * v0; acc1 += w1 * v1; acc2 += w2 * v2; acc3 += w3 * v3;
            acc0 += w4 * v4; acc1 += w5 * v5; acc2 += w6 * v6; acc3 += w7 * v7;
        }
        for (; jj < m; ++jj) {
            int a0 = __shfl(si, jj); float w0 = __shfl(wl, jj);
            acc0 += w0 * b2f(hp[(size_t)a0 * 64 + lane]);
        }
    }
    float v = dinv[n] * (acc0 + acc1 + acc2 + acc3) + b[lane];
    out[(size_t)n * 64 + lane] = v > 0.f ? v : 0.f;
}

extern "C" void kernel_launch(void* const* d_in, const int* in_sizes, int n_in,
                              void* d_out, int out_size, void* d_ws, size_t ws_size,
                              hipStream_t stream) {
    const float* x  = (const float*)d_in[0];
    const int*   ei = (const int*)d_in[1];    // int32 [2, NE] flat
    const float* ew = (const float*)d_in[2];
    const float* W0 = (const float*)d_in[3];
    const float* b0 = (const float*)d_in[4];
    const float* W1 = (const float*)d_in[5];
    const float* b1 = (const float*)d_in[6];
    const float* W2 = (const float*)d_in[7];
    const float* b2 = (const float*)d_in[8];
    float*       out = (float*)d_out;

    const int* src = ei;
    const int* dst = ei + NE;

    // workspace layout, ~13.6 MB total
    int*   counts    = (int*)d_ws;                   // NN   (memset to 0)
    int*   row_start = counts + NN;                  // NN+1
    int*   cursor    = row_start + NN + 1;           // NN
    int*   blocksum  = cursor + NN;                  // 128
    int*   blockoff  = blocksum + 128;               // 128 (+1 pad for int2 align)
    int2*  csr_pk    = (int2*)(blockoff + 129);      // NE pairs (8B each)
    float* dinv      = (float*)(csr_pk + NE);        // NN
    unsigned short* hp = (unsigned short*)(dinv + NN); // NN*64 bf16

    // ---- CSR build (once; shared by all 3 layers) ----
    hipMemsetAsync(counts, 0, NN * sizeof(int), stream);
    hist_kernel<<<(NE + 255) / 256, 256, 0, stream>>>(dst, counts);
    scan_partial_kernel<<<SCAN_B, 256, 0, stream>>>(counts, blocksum);
    scan_block_kernel<<<1, 128, 0, stream>>>(blocksum, blockoff);
    scan_emit_kernel<<<SCAN_B, 256, 0, stream>>>(counts, blockoff, row_start, cursor);
    fill_kernel<<<(NE + 255) / 256, 256, 0, stream>>>(src, dst, ew, cursor, csr_pk);
    wdeg_kernel<<<(NN + 255) / 256, 256, 0, stream>>>(row_start, csr_pk, dinv);

    // ---- layer 0: x -> out ----
    gemm_pre_kernel<<<NN / 16, 256, 0, stream>>>(x, W0, dinv, hp);
    gather_kernel<<<NN / 4, 256, 0, stream>>>(row_start, csr_pk, dinv, hp, b0, out);

    // ---- layer 1: out -> out (gemm consumes out before gather overwrites; stream-ordered) ----
    gemm_pre_kernel<<<NN / 16, 256, 0, stream>>>(out, W1, dinv, hp);
    gather_kernel<<<NN / 4, 256, 0, stream>>>(row_start, csr_pk, dinv, hp, b1, out);

    // ---- layer 2: out -> out ----
    gemm_pre_kernel<<<NN / 16, 256, 0, stream>>>(out, W2, dinv, hp);
    gather_kernel<<<NN / 4, 256, 0, stream>>>(row_start, csr_pk, dinv, hp, b2, out);
}

// Round 6
// 267.358 us; speedup vs baseline: 2.9157x; 1.1739x over previous
//
#include <hip/hip_runtime.h>

#define NN 50000
#define NE 800000
#define D  64
#define NB 782        // buckets of 64 nodes: ceil(50000/64)
#define NBLK 64       // phase-1/2 blocks
#define CHUNK 12500   // NBLK * CHUNK == NE exactly

// bf16 helpers (raw ushort storage, fp32 math)
__device__ __forceinline__ float b2f(unsigned short u) {
    return __uint_as_float((unsigned)u << 16);
}
__device__ __forceinline__ unsigned short f2b(float f) {   // round-to-nearest-even
    unsigned u = __float_as_uint(f);
    return (unsigned short)((u + 0x7FFFu + ((u >> 16) & 1u)) >> 16);
}

// ---- phase 1: per-chunk LDS histogram over 782 buckets ----
__global__ __launch_bounds__(256) void p1_hist(const int* __restrict__ src,
        const int* __restrict__ dst, int* __restrict__ M) {
    __shared__ int lh[NB];
    int t = threadIdx.x;
    for (int i = t; i < NB; i += 256) lh[i] = 0;
    __syncthreads();
    int e0 = blockIdx.x * CHUNK, e1 = e0 + CHUNK;
    for (int e = e0 + t; e < e1; e += 256) {
        unsigned d = (unsigned)dst[e];
        unsigned s = (unsigned)src[e];
        if (d < NN && s < NN) atomicAdd(&lh[d >> 6], 1);
    }
    __syncthreads();
    for (int i = t; i < NB; i += 256) M[blockIdx.x * NB + i] = lh[i];
}

// ---- scan: M[blk][b] -> global start offset for (blk,b); bucket_base[b] ----
__global__ __launch_bounds__(1024) void p_scan(int* __restrict__ M, int* __restrict__ bucket_base) {
    __shared__ int tot[1024];
    int b = threadIdx.x;
    int sum = 0;
    if (b < NB) {
        for (int k = 0; k < NBLK; ++k) {
            int v = M[k * NB + b];
            M[k * NB + b] = sum;     // exclusive within bucket
            sum += v;
        }
    }
    tot[b] = (b < NB) ? sum : 0;
    __syncthreads();
    for (int off = 1; off < 1024; off <<= 1) {     // Hillis-Steele inclusive
        int add = (b >= off) ? tot[b - off] : 0;
        __syncthreads();
        tot[b] += add;
        __syncthreads();
    }
    if (b < NB) {
        int base = tot[b] - sum;     // exclusive
        bucket_base[b] = base;
        for (int k = 0; k < NBLK; ++k) M[k * NB + b] += base;
        if (b == NB - 1) bucket_base[NB] = tot[b];   // total valid edges
    }
}

// ---- phase 2: scatter edges to bucket-sorted staging (LDS cursors, no global atomics) ----
__global__ __launch_bounds__(256) void p2_scatter(const int* __restrict__ src,
        const int* __restrict__ dst, const float* __restrict__ w,
        const int* __restrict__ M, int2* __restrict__ stage) {
    __shared__ int lcur[NB];
    int t = threadIdx.x;
    for (int i = t; i < NB; i += 256) lcur[i] = M[blockIdx.x * NB + i];
    __syncthreads();
    int e0 = blockIdx.x * CHUNK, e1 = e0 + CHUNK;
    for (int e = e0 + t; e < e1; e += 256) {
        unsigned d = (unsigned)dst[e];
        unsigned s = (unsigned)src[e];
        if (d < NN && s < NN) {
            int pos = atomicAdd(&lcur[d >> 6], 1);          // LDS atomic
            int2 pk;
            pk.x = (int)(s | ((d & 63u) << 16));            // src fits 16 bits
            pk.y = __float_as_int(w[e]);
            stage[pos] = pk;
        }
    }
}

// ---- phase 3: sort each 64-node bucket into exact rows; emit row_start ----
__global__ __launch_bounds__(256) void p3_sort(const int2* __restrict__ stage,
        const int* __restrict__ bucket_base, int2* __restrict__ csr,
        int* __restrict__ row_start) {
    __shared__ int hist[64];
    __shared__ int roff[64];
    int b = blockIdx.x;
    int t = threadIdx.x;
    int g0 = bucket_base[b], g1 = bucket_base[b + 1];
    if (t < 64) hist[t] = 0;
    __syncthreads();
    for (int j = g0 + t; j < g1; j += 256)
        atomicAdd(&hist[(stage[j].x >> 16) & 63], 1);
    __syncthreads();
    if (t == 0) {
        int s = 0;
        for (int r = 0; r < 64; ++r) { roff[r] = s; s += hist[r]; }
    }
    __syncthreads();
    if (t < 64) {
        int n = b * 64 + t;
        if (n < NN) row_start[n] = g0 + roff[t];
        hist[t] = g0 + roff[t];     // reuse as global cursor
    }
    __syncthreads();
    for (int j = g0 + t; j < g1; j += 256) {
        int2 pk = stage[j];
        int r = (pk.x >> 16) & 63;
        int pos = atomicAdd(&hist[r], 1);
        csr[pos] = make_int2(pk.x & 0xFFFF, pk.y);
    }
    if (b == 0 && t == 0) row_start[NN] = bucket_base[NB];
}

// dinv[n] = rsqrt(1 + sum_{row n} w)  — contiguous reads, no atomics
__global__ void wdeg_kernel(const int* __restrict__ row_start, const int2* __restrict__ csr,
                            float* __restrict__ dinv) {
    int n = blockIdx.x * blockDim.x + threadIdx.x;
    if (n < NN) {
        int s0 = row_start[n], s1 = row_start[n + 1];
        float s = 0.f;
        for (int j = s0; j < s1; ++j) s += __int_as_float(csr[j].y);
        dinv[n] = rsqrtf(s + 1.0f);
    }
}

// hp[N,64] = bf16( dinv[r] * (x[N,64] @ W[64,64]) ); 16 rows/block
__global__ __launch_bounds__(256) void gemm_pre_kernel(const float* __restrict__ x,
        const float* __restrict__ W, const float* __restrict__ dinv,
        unsigned short* __restrict__ hp) {
    __shared__ float xs[16][64];
    int t = threadIdx.x;
    int base = blockIdx.x * 16;
    for (int idx = t; idx < 16 * 64; idx += 256)
        xs[idx >> 6][idx & 63] = x[(size_t)(base + (idx >> 6)) * 64 + (idx & 63)];
    __syncthreads();
    int col = t & 63, rq = t >> 6;
    float wc[64];
#pragma unroll
    for (int k = 0; k < 64; ++k) wc[k] = W[k * 64 + col];
    float acc0 = 0.f, acc1 = 0.f, acc2 = 0.f, acc3 = 0.f;
#pragma unroll
    for (int k = 0; k < 64; ++k) {
        float wk = wc[k];
        acc0 += xs[rq     ][k] * wk;
        acc1 += xs[rq +  4][k] * wk;
        acc2 += xs[rq +  8][k] * wk;
        acc3 += xs[rq + 12][k] * wk;
    }
    int r = base + rq;
    hp[(size_t)(r     ) * 64 + col] = f2b(dinv[r     ] * acc0);
    hp[(size_t)(r +  4) * 64 + col] = f2b(dinv[r +  4] * acc1);
    hp[(size_t)(r +  8) * 64 + col] = f2b(dinv[r +  8] * acc2);
    hp[(size_t)(r + 12) * 64 + col] = f2b(dinv[r + 12] * acc3);
}

// half-wave per node (lane = feature pair), 2 nodes/wave, 8 rows in flight per half
__global__ __launch_bounds__(256) void gather_kernel(const int* __restrict__ row_start,
        const int2* __restrict__ csr, const float* __restrict__ dinv,
        const unsigned* __restrict__ hp32, const float* __restrict__ bias,
        float* __restrict__ out) {
    int t = threadIdx.x;
    int lane = t & 63;
    int h = lane >> 5;              // half id within wave
    int fl = lane & 31;             // feature-pair id
    int n = blockIdx.x * 8 + ((t >> 6) << 1) + h;   // 4 waves x 2 nodes
    int hbase = h << 5;
    int s0 = row_start[n], s1 = row_start[n + 1];
    unsigned self = hp32[(size_t)n * 32 + fl];
    float ax = b2f((unsigned short)(self & 0xFFFF));
    float ay = b2f((unsigned short)(self >> 16));
    float bx = 0.f, by = 0.f;
    for (int base = s0; base < s1; base += 32) {
        int j = base + fl;
        int si = 0; float wl = 0.f;
        if (j < s1) {
            int2 pk = csr[j];
            si = pk.x;
            wl = __int_as_float(pk.y);
        }
        int m = s1 - base; if (m > 32) m = 32;
        int jj = 0;
        for (; jj + 8 <= m; jj += 8) {
            int a0 = __shfl(si, hbase + jj + 0); float w0 = __shfl(wl, hbase + jj + 0);
            int a1 = __shfl(si, hbase + jj + 1); float w1 = __shfl(wl, hbase + jj + 1);
            int a2 = __shfl(si, hbase + jj + 2); float w2 = __shfl(wl, hbase + jj + 2);
            int a3 = __shfl(si, hbase + jj + 3); float w3 = __shfl(wl, hbase + jj + 3);
            int a4 = __shfl(si, hbase + jj + 4); float w4 = __shfl(wl, hbase + jj + 4);
            int a5 = __shfl(si, hbase + jj + 5); float w5 = __shfl(wl, hbase + jj + 5);
            int a6 = __shfl(si, hbase + jj + 6); float w6 = __shfl(wl, hbase + jj + 6);
            int a7 = __shfl(si, hbase + jj + 7); float w7 = __shfl(wl, hbase + jj + 7);
            unsigned u0 = hp32[(size_t)a0 * 32 + fl];
            unsigned u1 = hp32[(size_t)a1 * 32 + fl];
            unsigned u2 = hp32[(size_t)a2 * 32 + fl];
            unsigned u3 = hp32[(size_t)a3 * 32 + fl];
            unsigned u4 = hp32[(size_t)a4 * 32 + fl];
            unsigned u5 = hp32[(size_t)a5 * 32 + fl];
            unsigned u6 = hp32[(size_t)a6 * 32 + fl];
            unsigned u7 = hp32[(size_t)a7 * 32 + fl];
            ax += w0 * b2f((unsigned short)(u0 & 0xFFFF)); ay += w0 * b2f((unsigned short)(u0 >> 16));
            bx += w1 * b2f((unsigned short)(u1 & 0xFFFF)); by += w1 * b2f((unsigned short)(u1 >> 16));
            ax += w2 * b2f((unsigned short)(u2 & 0xFFFF)); ay += w2 * b2f((unsigned short)(u2 >> 16));
            bx += w3 * b2f((unsigned short)(u3 & 0xFFFF)); by += w3 * b2f((unsigned short)(u3 >> 16));
            ax += w4 * b2f((unsigned short)(u4 & 0xFFFF)); ay += w4 * b2f((unsigned short)(u4 >> 16));
            bx += w5 * b2f((unsigned short)(u5 & 0xFFFF)); by += w5 * b2f((unsigned short)(u5 >> 16));
            ax += w6 * b2f((unsigned short)(u6 & 0xFFFF)); ay += w6 * b2f((unsigned short)(u6 >> 16));
            bx += w7 * b2f((unsigned short)(u7 & 0xFFFF)); by += w7 * b2f((unsigned short)(u7 >> 16));
        }
        for (; jj < m; ++jj) {
            int a0 = __shfl(si, hbase + jj); float w0 = __shfl(wl, hbase + jj);
            unsigned u0 = hp32[(size_t)a0 * 32 + fl];
            ax += w0 * b2f((unsigned short)(u0 & 0xFFFF));
            ay += w0 * b2f((unsigned short)(u0 >> 16));
        }
    }
    float dv = dinv[n];
    float2 bb = ((const float2*)bias)[fl];
    float2 r;
    r.x = dv * (ax + bx) + bb.x;
    r.y = dv * (ay + by) + bb.y;
    r.x = r.x > 0.f ? r.x : 0.f;
    r.y = r.y > 0.f ? r.y : 0.f;
    ((float2*)out)[(size_t)n * 32 + fl] = r;
}

extern "C" void kernel_launch(void* const* d_in, const int* in_sizes, int n_in,
                              void* d_out, int out_size, void* d_ws, size_t ws_size,
                              hipStream_t stream) {
    const float* x  = (const float*)d_in[0];
    const int*   ei = (const int*)d_in[1];    // int32 [2, NE] flat
    const float* ew = (const float*)d_in[2];
    const float* W0 = (const float*)d_in[3];
    const float* b0 = (const float*)d_in[4];
    const float* W1 = (const float*)d_in[5];
    const float* b1 = (const float*)d_in[6];
    const float* W2 = (const float*)d_in[7];
    const float* b2 = (const float*)d_in[8];
    float*       out = (float*)d_out;

    const int* src = ei;
    const int* dst = ei + NE;

    // workspace layout (int2 arrays first for 8B alignment), ~19.9 MB total
    int2*  stage      = (int2*)d_ws;                     // NE
    int2*  csr        = stage + NE;                      // NE
    int*   M          = (int*)(csr + NE);                // NBLK*NB
    int*   bucket_base= M + NBLK * NB;                   // NB+1
    int*   row_start  = bucket_base + NB + 1;            // NN+1
    float* dinv       = (float*)(row_start + NN + 1);    // NN
    unsigned short* hp = (unsigned short*)(dinv + NN);   // NN*64 bf16

    // ---- CSR build (atomic-free; once, shared by all 3 layers) ----
    p1_hist<<<NBLK, 256, 0, stream>>>(src, dst, M);
    p_scan<<<1, 1024, 0, stream>>>(M, bucket_base);
    p2_scatter<<<NBLK, 256, 0, stream>>>(src, dst, ew, M, stage);
    p3_sort<<<NB, 256, 0, stream>>>(stage, bucket_base, csr, row_start);
    wdeg_kernel<<<(NN + 255) / 256, 256, 0, stream>>>(row_start, csr, dinv);

    // ---- layer 0: x -> out ----
    gemm_pre_kernel<<<NN / 16, 256, 0, stream>>>(x, W0, dinv, hp);
    gather_kernel<<<NN / 8, 256, 0, stream>>>(row_start, csr, dinv, (const unsigned*)hp, b0, out);

    // ---- layer 1: out -> out (gemm consumes out before gather overwrites; stream-ordered) ----
    gemm_pre_kernel<<<NN / 16, 256, 0, stream>>>(out, W1, dinv, hp);
    gather_kernel<<<NN / 8, 256, 0, stream>>>(row_start, csr, dinv, (const unsigned*)hp, b1, out);

    // ---- layer 2: out -> out ----
    gemm_pre_kernel<<<NN / 16, 256, 0, stream>>>(out, W2, dinv, hp);
    gather_kernel<<<NN / 8, 256, 0, stream>>>(row_start, csr, dinv, (const unsigned*)hp, b2, out);
}

// Round 7
// 233.376 us; speedup vs baseline: 3.3402x; 1.1456x over previous
//
#include <hip/hip_runtime.h>

#define NN 50000
#define NE 800000
#define D  64
#define NB 782        // buckets of 64 nodes: ceil(50000/64)
#define NBLK 256      // phase-1/2 blocks
#define CHUNK 3125    // NBLK * CHUNK == NE exactly

// bf16 helpers (raw ushort storage, fp32 math)
__device__ __forceinline__ float b2f(unsigned short u) {
    return __uint_as_float((unsigned)u << 16);
}
__device__ __forceinline__ unsigned short f2b(float f) {   // round-to-nearest-even
    unsigned u = __float_as_uint(f);
    return (unsigned short)((u + 0x7FFFu + ((u >> 16) & 1u)) >> 16);
}

// ---- phase 1: per-chunk LDS histogram over 782 buckets ----
__global__ __launch_bounds__(256) void p1_hist(const int* __restrict__ dst, int* __restrict__ M) {
    __shared__ int lh[NB];
    int t = threadIdx.x;
    for (int i = t; i < NB; i += 256) lh[i] = 0;
    __syncthreads();
    int e0 = blockIdx.x * CHUNK;
    for (int e = e0 + t; e < e0 + CHUNK; e += 256) {
        unsigned d = (unsigned)dst[e];
        if (d < NN) atomicAdd(&lh[d >> 6], 1);
    }
    __syncthreads();
    for (int i = t; i < NB; i += 256) M[blockIdx.x * NB + i] = lh[i];
}

// ---- scan A: one block per bucket — scan the 256 chunk-counts of column b ----
__global__ __launch_bounds__(256) void p_scan_a(int* __restrict__ M, int* __restrict__ btot) {
    __shared__ int sd[256];
    int b = blockIdx.x, t = threadIdx.x;
    int v = M[t * NB + b];
    sd[t] = v;
    __syncthreads();
    for (int off = 1; off < 256; off <<= 1) {
        int add = (t >= off) ? sd[t - off] : 0;
        __syncthreads();
        sd[t] += add;
        __syncthreads();
    }
    M[t * NB + b] = sd[t] - v;            // exclusive within bucket
    if (t == 255) btot[b] = sd[255];
}

// ---- scan B: exclusive scan of 782 bucket totals ----
__global__ __launch_bounds__(1024) void p_scan_b(const int* __restrict__ btot,
                                                 int* __restrict__ bucket_base) {
    __shared__ int sd[1024];
    int t = threadIdx.x;
    int v = (t < NB) ? btot[t] : 0;
    sd[t] = v;
    __syncthreads();
    for (int off = 1; off < 1024; off <<= 1) {
        int add = (t >= off) ? sd[t - off] : 0;
        __syncthreads();
        sd[t] += add;
        __syncthreads();
    }
    if (t < NB) bucket_base[t] = sd[t] - v;
    if (t == NB - 1) bucket_base[NB] = sd[t];
}

// ---- phase 2: scatter edges to bucket-sorted staging (LDS cursors, no global atomics) ----
__global__ __launch_bounds__(256) void p2_scatter(const int* __restrict__ src,
        const int* __restrict__ dst, const float* __restrict__ w,
        const int* __restrict__ M, const int* __restrict__ bucket_base,
        int2* __restrict__ stage) {
    __shared__ int lcur[NB];
    int t = threadIdx.x;
    for (int i = t; i < NB; i += 256)
        lcur[i] = M[blockIdx.x * NB + i] + bucket_base[i];
    __syncthreads();
    int e0 = blockIdx.x * CHUNK;
    for (int e = e0 + t; e < e0 + CHUNK; e += 256) {
        unsigned d = (unsigned)dst[e];
        unsigned s = (unsigned)src[e];
        if (d < NN) {
            int pos = atomicAdd(&lcur[d >> 6], 1);          // LDS atomic
            int2 pk;
            pk.x = (int)((s & 0xFFFFu) | ((d & 63u) << 16)); // src fits 16 bits
            pk.y = __float_as_int(w[e]);
            stage[pos] = pk;
        }
    }
}

// ---- phase 3: sort each 64-node bucket into exact rows; emit row_start + dinv ----
__global__ __launch_bounds__(256) void p3_sort(const int2* __restrict__ stage,
        const int* __restrict__ bucket_base, int2* __restrict__ csr,
        int* __restrict__ row_start, float* __restrict__ dinv) {
    __shared__ int   hist[64];
    __shared__ int   cur[64];
    __shared__ float wsum[64];
    int b = blockIdx.x, t = threadIdx.x;
    int g0 = bucket_base[b], g1 = bucket_base[b + 1];
    if (t < 64) { hist[t] = 0; wsum[t] = 0.f; }
    __syncthreads();
    for (int j = g0 + t; j < g1; j += 256) {
        int2 pk = stage[j];
        int r = (pk.x >> 16) & 63;
        atomicAdd(&hist[r], 1);
        atomicAdd(&wsum[r], __int_as_float(pk.y));   // fused weighted degree
    }
    __syncthreads();
    if (t == 0) {
        int s = g0;
        for (int r = 0; r < 64; ++r) { cur[r] = s; s += hist[r]; }
    }
    __syncthreads();
    if (t < 64) {
        int n = b * 64 + t;
        if (n < NN) {
            row_start[n] = cur[t];
            dinv[n] = rsqrtf(wsum[t] + 1.0f);
        }
    }
    __syncthreads();
    for (int j = g0 + t; j < g1; j += 256) {
        int2 pk = stage[j];
        int r = (pk.x >> 16) & 63;
        int pos = atomicAdd(&cur[r], 1);
        csr[pos] = make_int2(pk.x & 0xFFFF, pk.y);
    }
    if (b == 0 && t == 0) row_start[NN] = bucket_base[NB];
}

// hp[N,64] = bf16( dinv[r] * (x[N,64] @ W[64,64]) ); 16 rows/block
__global__ __launch_bounds__(256) void gemm_pre_kernel(const float* __restrict__ x,
        const float* __restrict__ W, const float* __restrict__ dinv,
        unsigned short* __restrict__ hp) {
    __shared__ float xs[16][64];
    int t = threadIdx.x;
    int base = blockIdx.x * 16;
    for (int idx = t; idx < 16 * 64; idx += 256)
        xs[idx >> 6][idx & 63] = x[(size_t)(base + (idx >> 6)) * 64 + (idx & 63)];
    __syncthreads();
    int col = t & 63, rq = t >> 6;
    float wc[64];
#pragma unroll
    for (int k = 0; k < 64; ++k) wc[k] = W[k * 64 + col];
    float acc0 = 0.f, acc1 = 0.f, acc2 = 0.f, acc3 = 0.f;
#pragma unroll
    for (int k = 0; k < 64; ++k) {
        float wk = wc[k];
        acc0 += xs[rq     ][k] * wk;
        acc1 += xs[rq +  4][k] * wk;
        acc2 += xs[rq +  8][k] * wk;
        acc3 += xs[rq + 12][k] * wk;
    }
    int r = base + rq;
    hp[(size_t)(r     ) * 64 + col] = f2b(dinv[r     ] * acc0);
    hp[(size_t)(r +  4) * 64 + col] = f2b(dinv[r +  4] * acc1);
    hp[(size_t)(r +  8) * 64 + col] = f2b(dinv[r +  8] * acc2);
    hp[(size_t)(r + 12) * 64 + col] = f2b(dinv[r + 12] * acc3);
}

// half-wave per node (lane = feature pair), 2 nodes/wave, 8 rows in flight per half
__global__ __launch_bounds__(256) void gather_kernel(const int* __restrict__ row_start,
        const int2* __restrict__ csr, const float* __restrict__ dinv,
        const unsigned* __restrict__ hp32, const float* __restrict__ bias,
        float* __restrict__ out) {
    int t = threadIdx.x;
    int lane = t & 63;
    int h = lane >> 5;              // half id within wave
    int fl = lane & 31;             // feature-pair id
    int n = blockIdx.x * 8 + ((t >> 6) << 1) + h;   // 4 waves x 2 nodes
    int hbase = h << 5;
    int s0 = row_start[n], s1 = row_start[n + 1];
    unsigned self = hp32[(size_t)n * 32 + fl];
    float ax = b2f((unsigned short)(self & 0xFFFF));
    float ay = b2f((unsigned short)(self >> 16));
    float bx = 0.f, by = 0.f;
    for (int base = s0; base < s1; base += 32) {
        int j = base + fl;
        int si = 0; float wl = 0.f;
        if (j < s1) {
            int2 pk = csr[j];
            si = pk.x;
            wl = __int_as_float(pk.y);
        }
        int m = s1 - base; if (m > 32) m = 32;
        int jj = 0;
        for (; jj + 8 <= m; jj += 8) {
            int a0 = __shfl(si, hbase + jj + 0); float w0 = __shfl(wl, hbase + jj + 0);
            int a1 = __shfl(si, hbase + jj + 1); float w1 = __shfl(wl, hbase + jj + 1);
            int a2 = __shfl(si, hbase + jj + 2); float w2 = __shfl(wl, hbase + jj + 2);
            int a3 = __shfl(si, hbase + jj + 3); float w3 = __shfl(wl, hbase + jj + 3);
            int a4 = __shfl(si, hbase + jj + 4); float w4 = __shfl(wl, hbase + jj + 4);
            int a5 = __shfl(si, hbase + jj + 5); float w5 = __shfl(wl, hbase + jj + 5);
            int a6 = __shfl(si, hbase + jj + 6); float w6 = __shfl(wl, hbase + jj + 6);
            int a7 = __shfl(si, hbase + jj + 7); float w7 = __shfl(wl, hbase + jj + 7);
            unsigned u0 = hp32[(size_t)a0 * 32 + fl];
            unsigned u1 = hp32[(size_t)a1 * 32 + fl];
            unsigned u2 = hp32[(size_t)a2 * 32 + fl];
            unsigned u3 = hp32[(size_t)a3 * 32 + fl];
            unsigned u4 = hp32[(size_t)a4 * 32 + fl];
            unsigned u5 = hp32[(size_t)a5 * 32 + fl];
            unsigned u6 = hp32[(size_t)a6 * 32 + fl];
            unsigned u7 = hp32[(size_t)a7 * 32 + fl];
            ax += w0 * b2f((unsigned short)(u0 & 0xFFFF)); ay += w0 * b2f((unsigned short)(u0 >> 16));
            bx += w1 * b2f((unsigned short)(u1 & 0xFFFF)); by += w1 * b2f((unsigned short)(u1 >> 16));
            ax += w2 * b2f((unsigned short)(u2 & 0xFFFF)); ay += w2 * b2f((unsigned short)(u2 >> 16));
            bx += w3 * b2f((unsigned short)(u3 & 0xFFFF)); by += w3 * b2f((unsigned short)(u3 >> 16));
            ax += w4 * b2f((unsigned short)(u4 & 0xFFFF)); ay += w4 * b2f((unsigned short)(u4 >> 16));
            bx += w5 * b2f((unsigned short)(u5 & 0xFFFF)); by += w5 * b2f((unsigned short)(u5 >> 16));
            ax += w6 * b2f((unsigned short)(u6 & 0xFFFF)); ay += w6 * b2f((unsigned short)(u6 >> 16));
            bx += w7 * b2f((unsigned short)(u7 & 0xFFFF)); by += w7 * b2f((unsigned short)(u7 >> 16));
        }
        for (; jj < m; ++jj) {
            int a0 = __shfl(si, hbase + jj); float w0 = __shfl(wl, hbase + jj);
            unsigned u0 = hp32[(size_t)a0 * 32 + fl];
            ax += w0 * b2f((unsigned short)(u0 & 0xFFFF));
            ay += w0 * b2f((unsigned short)(u0 >> 16));
        }
    }
    float dv = dinv[n];
    float2 bb = ((const float2*)bias)[fl];
    float2 r;
    r.x = dv * (ax + bx) + bb.x;
    r.y = dv * (ay + by) + bb.y;
    r.x = r.x > 0.f ? r.x : 0.f;
    r.y = r.y > 0.f ? r.y : 0.f;
    ((float2*)out)[(size_t)n * 32 + fl] = r;
}

extern "C" void kernel_launch(void* const* d_in, const int* in_sizes, int n_in,
                              void* d_out, int out_size, void* d_ws, size_t ws_size,
                              hipStream_t stream) {
    const float* x  = (const float*)d_in[0];
    const int*   ei = (const int*)d_in[1];    // int32 [2, NE] flat
    const float* ew = (const float*)d_in[2];
    const float* W0 = (const float*)d_in[3];
    const float* b0 = (const float*)d_in[4];
    const float* W1 = (const float*)d_in[5];
    const float* b1 = (const float*)d_in[6];
    const float* W2 = (const float*)d_in[7];
    const float* b2 = (const float*)d_in[8];
    float*       out = (float*)d_out;

    const int* src = ei;
    const int* dst = ei + NE;

    // workspace layout (int2 arrays first for 8B alignment), ~21 MB total
    int2*  stage       = (int2*)d_ws;                    // NE
    int2*  csr         = stage + NE;                     // NE
    int*   M           = (int*)(csr + NE);               // NBLK*NB
    int*   btot        = M + NBLK * NB;                  // NB
    int*   bucket_base = btot + NB;                      // NB+1
    int*   row_start   = bucket_base + NB + 1;           // NN+1
    float* dinv        = (float*)(row_start + NN + 1);   // NN
    unsigned short* hp = (unsigned short*)(dinv + NN);   // NN*64 bf16

    // ---- CSR build (atomic-free on globals; once, shared by all 3 layers) ----
    p1_hist<<<NBLK, 256, 0, stream>>>(dst, M);
    p_scan_a<<<NB, 256, 0, stream>>>(M, btot);
    p_scan_b<<<1, 1024, 0, stream>>>(btot, bucket_base);
    p2_scatter<<<NBLK, 256, 0, stream>>>(src, dst, ew, M, bucket_base, stage);
    p3_sort<<<NB, 256, 0, stream>>>(stage, bucket_base, csr, row_start, dinv);

    // ---- layer 0: x -> out ----
    gemm_pre_kernel<<<NN / 16, 256, 0, stream>>>(x, W0, dinv, hp);
    gather_kernel<<<NN / 8, 256, 0, stream>>>(row_start, csr, dinv, (const unsigned*)hp, b0, out);

    // ---- layer 1: out -> out (gemm consumes out before gather overwrites; stream-ordered) ----
    gemm_pre_kernel<<<NN / 16, 256, 0, stream>>>(out, W1, dinv, hp);
    gather_kernel<<<NN / 8, 256, 0, stream>>>(row_start, csr, dinv, (const unsigned*)hp, b1, out);

    // ---- layer 2: out -> out ----
    gemm_pre_kernel<<<NN / 16, 256, 0, stream>>>(out, W2, dinv, hp);
    gather_kernel<<<NN / 8, 256, 0, stream>>>(row_start, csr, dinv, (const unsigned*)hp, b2, out);
}

// Round 8
// 228.951 us; speedup vs baseline: 3.4048x; 1.0193x over previous
//
#include <hip/hip_runtime.h>

#define NN 50000
#define NE 800000
#define D  64
#define NB 782        // buckets of 64 nodes: ceil(50000/64)
#define NBLK 256      // phase-1/2 blocks
#define CHUNK 3125    // NBLK * CHUNK == NE exactly

// bf16 helpers (raw ushort storage, fp32 math)
__device__ __forceinline__ float b2f(unsigned short u) {
    return __uint_as_float((unsigned)u << 16);
}
__device__ __forceinline__ float blo(unsigned u) { return __uint_as_float(u << 16); }
__device__ __forceinline__ float bhi(unsigned u) { return __uint_as_float(u & 0xFFFF0000u); }
__device__ __forceinline__ unsigned short f2b(float f) {   // round-to-nearest-even
    unsigned u = __float_as_uint(f);
    return (unsigned short)((u + 0x7FFFu + ((u >> 16) & 1u)) >> 16);
}

// ---- phase 1: per-chunk LDS histogram over 782 buckets ----
__global__ __launch_bounds__(256) void p1_hist(const int* __restrict__ dst, int* __restrict__ M) {
    __shared__ int lh[NB];
    int t = threadIdx.x;
    for (int i = t; i < NB; i += 256) lh[i] = 0;
    __syncthreads();
    int e0 = blockIdx.x * CHUNK;
    for (int e = e0 + t; e < e0 + CHUNK; e += 256) {
        unsigned d = (unsigned)dst[e];
        if (d < NN) atomicAdd(&lh[d >> 6], 1);
    }
    __syncthreads();
    for (int i = t; i < NB; i += 256) M[blockIdx.x * NB + i] = lh[i];
}

// ---- scan A: one block per bucket — scan the 256 chunk-counts of column b ----
__global__ __launch_bounds__(256) void p_scan_a(int* __restrict__ M, int* __restrict__ btot) {
    __shared__ int sd[256];
    int b = blockIdx.x, t = threadIdx.x;
    int v = M[t * NB + b];
    sd[t] = v;
    __syncthreads();
    for (int off = 1; off < 256; off <<= 1) {
        int add = (t >= off) ? sd[t - off] : 0;
        __syncthreads();
        sd[t] += add;
        __syncthreads();
    }
    M[t * NB + b] = sd[t] - v;            // exclusive within bucket
    if (t == 255) btot[b] = sd[255];
}

// ---- scan B: exclusive scan of 782 bucket totals ----
__global__ __launch_bounds__(1024) void p_scan_b(const int* __restrict__ btot,
                                                 int* __restrict__ bucket_base) {
    __shared__ int sd[1024];
    int t = threadIdx.x;
    int v = (t < NB) ? btot[t] : 0;
    sd[t] = v;
    __syncthreads();
    for (int off = 1; off < 1024; off <<= 1) {
        int add = (t >= off) ? sd[t - off] : 0;
        __syncthreads();
        sd[t] += add;
        __syncthreads();
    }
    if (t < NB) bucket_base[t] = sd[t] - v;
    if (t == NB - 1) bucket_base[NB] = sd[t];
}

// ---- phase 2: scatter edges to bucket-sorted staging (LDS cursors, no global atomics) ----
__global__ __launch_bounds__(256) void p2_scatter(const int* __restrict__ src,
        const int* __restrict__ dst, const float* __restrict__ w,
        const int* __restrict__ M, const int* __restrict__ bucket_base,
        int2* __restrict__ stage) {
    __shared__ int lcur[NB];
    int t = threadIdx.x;
    for (int i = t; i < NB; i += 256)
        lcur[i] = M[blockIdx.x * NB + i] + bucket_base[i];
    __syncthreads();
    int e0 = blockIdx.x * CHUNK;
    for (int e = e0 + t; e < e0 + CHUNK; e += 256) {
        unsigned d = (unsigned)dst[e];
        unsigned s = (unsigned)src[e];
        if (d < NN) {
            int pos = atomicAdd(&lcur[d >> 6], 1);          // LDS atomic
            int2 pk;
            pk.x = (int)((s & 0xFFFFu) | ((d & 63u) << 16)); // src fits 16 bits
            pk.y = __float_as_int(w[e]);
            stage[pos] = pk;
        }
    }
}

// ---- phase 3: sort each 64-node bucket into exact rows; emit row_start + dinv ----
__global__ __launch_bounds__(256) void p3_sort(const int2* __restrict__ stage,
        const int* __restrict__ bucket_base, int2* __restrict__ csr,
        int* __restrict__ row_start, float* __restrict__ dinv) {
    __shared__ int   hist[64];
    __shared__ int   cur[64];
    __shared__ float wsum[64];
    int b = blockIdx.x, t = threadIdx.x;
    int g0 = bucket_base[b], g1 = bucket_base[b + 1];
    if (t < 64) { hist[t] = 0; wsum[t] = 0.f; }
    __syncthreads();
    for (int j = g0 + t; j < g1; j += 256) {
        int2 pk = stage[j];
        int r = (pk.x >> 16) & 63;
        atomicAdd(&hist[r], 1);
        atomicAdd(&wsum[r], __int_as_float(pk.y));   // fused weighted degree
    }
    __syncthreads();
    if (t == 0) {
        int s = g0;
        for (int r = 0; r < 64; ++r) { cur[r] = s; s += hist[r]; }
    }
    __syncthreads();
    if (t < 64) {
        int n = b * 64 + t;
        if (n < NN) {
            row_start[n] = cur[t];
            dinv[n] = rsqrtf(wsum[t] + 1.0f);
        }
    }
    __syncthreads();
    for (int j = g0 + t; j < g1; j += 256) {
        int2 pk = stage[j];
        int r = (pk.x >> 16) & 63;
        int pos = atomicAdd(&cur[r], 1);
        csr[pos] = make_int2(pk.x & 0xFFFF, pk.y);
    }
    if (b == 0 && t == 0) row_start[NN] = bucket_base[NB];
}

// hp[N,64] = bf16( dinv[r] * (x[N,64] @ W[64,64]) ); 16 rows/block
__global__ __launch_bounds__(256) void gemm_pre_kernel(const float* __restrict__ x,
        const float* __restrict__ W, const float* __restrict__ dinv,
        unsigned short* __restrict__ hp) {
    __shared__ float xs[16][64];
    int t = threadIdx.x;
    int base = blockIdx.x * 16;
    for (int idx = t; idx < 16 * 64; idx += 256)
        xs[idx >> 6][idx & 63] = x[(size_t)(base + (idx >> 6)) * 64 + (idx & 63)];
    __syncthreads();
    int col = t & 63, rq = t >> 6;
    float wc[64];
#pragma unroll
    for (int k = 0; k < 64; ++k) wc[k] = W[k * 64 + col];
    float acc0 = 0.f, acc1 = 0.f, acc2 = 0.f, acc3 = 0.f;
#pragma unroll
    for (int k = 0; k < 64; ++k) {
        float wk = wc[k];
        acc0 += xs[rq     ][k] * wk;
        acc1 += xs[rq +  4][k] * wk;
        acc2 += xs[rq +  8][k] * wk;
        acc3 += xs[rq + 12][k] * wk;
    }
    int r = base + rq;
    hp[(size_t)(r     ) * 64 + col] = f2b(dinv[r     ] * acc0);
    hp[(size_t)(r +  4) * 64 + col] = f2b(dinv[r +  4] * acc1);
    hp[(size_t)(r +  8) * 64 + col] = f2b(dinv[r +  8] * acc2);
    hp[(size_t)(r + 12) * 64 + col] = f2b(dinv[r + 12] * acc3);
}

// quarter-wave per node: 16 lanes x uint2 = one 128B bf16 row; 4 nodes/wave;
// each load instruction fetches 4 rows (512B) -> 2x MLP vs half-wave version.
__global__ __launch_bounds__(256) void gather_kernel(const int* __restrict__ row_start,
        const int2* __restrict__ csr, const float* __restrict__ dinv,
        const uint2* __restrict__ hp64, const float* __restrict__ bias,
        float* __restrict__ out) {
    int t = threadIdx.x;
    int lane = t & 63;
    int q = lane >> 4;              // quarter id within wave
    int fq = lane & 15;             // feature-quad id (4 feats)
    int n = blockIdx.x * 16 + ((t >> 6) << 2) + q;   // 4 waves x 4 nodes
    int qbase = q << 4;
    int s0 = row_start[n], s1 = row_start[n + 1];
    uint2 self = hp64[(size_t)n * 16 + fq];
    float ax = blo(self.x), ay = bhi(self.x), az = blo(self.y), aw = bhi(self.y);
    float bx = 0.f, by = 0.f, bz = 0.f, bw = 0.f;
    for (int base = s0; base < s1; base += 16) {
        int j = base + fq;
        int si = 0; float wl = 0.f;
        if (j < s1) {
            int2 pk = csr[j];
            si = pk.x;
            wl = __int_as_float(pk.y);
        }
        int m = s1 - base; if (m > 16) m = 16;
        int jj = 0;
        for (; jj + 4 <= m; jj += 4) {
            int a0 = __shfl(si, qbase + jj + 0); float w0 = __shfl(wl, qbase + jj + 0);
            int a1 = __shfl(si, qbase + jj + 1); float w1 = __shfl(wl, qbase + jj + 1);
            int a2 = __shfl(si, qbase + jj + 2); float w2 = __shfl(wl, qbase + jj + 2);
            int a3 = __shfl(si, qbase + jj + 3); float w3 = __shfl(wl, qbase + jj + 3);
            uint2 u0 = hp64[(size_t)a0 * 16 + fq];
            uint2 u1 = hp64[(size_t)a1 * 16 + fq];
            uint2 u2 = hp64[(size_t)a2 * 16 + fq];
            uint2 u3 = hp64[(size_t)a3 * 16 + fq];
            ax += w0 * blo(u0.x); ay += w0 * bhi(u0.x); az += w0 * blo(u0.y); aw += w0 * bhi(u0.y);
            bx += w1 * blo(u1.x); by += w1 * bhi(u1.x); bz += w1 * blo(u1.y); bw += w1 * bhi(u1.y);
            ax += w2 * blo(u2.x); ay += w2 * bhi(u2.x); az += w2 * blo(u2.y); aw += w2 * bhi(u2.y);
            bx += w3 * blo(u3.x); by += w3 * bhi(u3.x); bz += w3 * blo(u3.y); bw += w3 * bhi(u3.y);
        }
        for (; jj < m; ++jj) {
            int a0 = __shfl(si, qbase + jj); float w0 = __shfl(wl, qbase + jj);
            uint2 u0 = hp64[(size_t)a0 * 16 + fq];
            ax += w0 * blo(u0.x); ay += w0 * bhi(u0.x); az += w0 * blo(u0.y); aw += w0 * bhi(u0.y);
        }
    }
    float dv = dinv[n];
    float4 bb = ((const float4*)bias)[fq];
    float4 r;
    r.x = dv * (ax + bx) + bb.x;
    r.y = dv * (ay + by) + bb.y;
    r.z = dv * (az + bz) + bb.z;
    r.w = dv * (aw + bw) + bb.w;
    r.x = r.x > 0.f ? r.x : 0.f;
    r.y = r.y > 0.f ? r.y : 0.f;
    r.z = r.z > 0.f ? r.z : 0.f;
    r.w = r.w > 0.f ? r.w : 0.f;
    ((float4*)out)[(size_t)n * 16 + fq] = r;
}

extern "C" void kernel_launch(void* const* d_in, const int* in_sizes, int n_in,
                              void* d_out, int out_size, void* d_ws, size_t ws_size,
                              hipStream_t stream) {
    const float* x  = (const float*)d_in[0];
    const int*   ei = (const int*)d_in[1];    // int32 [2, NE] flat
    const float* ew = (const float*)d_in[2];
    const float* W0 = (const float*)d_in[3];
    const float* b0 = (const float*)d_in[4];
    const float* W1 = (const float*)d_in[5];
    const float* b1 = (const float*)d_in[6];
    const float* W2 = (const float*)d_in[7];
    const float* b2 = (const float*)d_in[8];
    float*       out = (float*)d_out;

    const int* src = ei;
    const int* dst = ei + NE;

    // workspace layout (int2 arrays first for 8B alignment), ~21 MB total
    int2*  stage       = (int2*)d_ws;                    // NE
    int2*  csr         = stage + NE;                     // NE
    int*   M           = (int*)(csr + NE);               // NBLK*NB
    int*   btot        = M + NBLK * NB;                  // NB
    int*   bucket_base = btot + NB;                      // NB+1
    int*   row_start   = bucket_base + NB + 1;           // NN+1
    float* dinv        = (float*)(row_start + NN + 1);   // NN
    unsigned short* hp = (unsigned short*)(dinv + NN);   // NN*64 bf16

    // ---- CSR build (no global atomics; once, shared by all 3 layers) ----
    p1_hist<<<NBLK, 256, 0, stream>>>(dst, M);
    p_scan_a<<<NB, 256, 0, stream>>>(M, btot);
    p_scan_b<<<1, 1024, 0, stream>>>(btot, bucket_base);
    p2_scatter<<<NBLK, 256, 0, stream>>>(src, dst, ew, M, bucket_base, stage);
    p3_sort<<<NB, 256, 0, stream>>>(stage, bucket_base, csr, row_start, dinv);

    // ---- layer 0: x -> out ----
    gemm_pre_kernel<<<NN / 16, 256, 0, stream>>>(x, W0, dinv, hp);
    gather_kernel<<<NN / 16, 256, 0, stream>>>(row_start, csr, dinv, (const uint2*)hp, b0, out);

    // ---- layer 1: out -> out (gemm consumes out before gather overwrites; stream-ordered) ----
    gemm_pre_kernel<<<NN / 16, 256, 0, stream>>>(out, W1, dinv, hp);
    gather_kernel<<<NN / 16, 256, 0, stream>>>(row_start, csr, dinv, (const uint2*)hp, b1, out);

    // ---- layer 2: out -> out ----
    gemm_pre_kernel<<<NN / 16, 256, 0, stream>>>(out, W2, dinv, hp);
    gather_kernel<<<NN / 16, 256, 0, stream>>>(row_start, csr, dinv, (const uint2*)hp, b2, out);
}